// Round 10
// baseline (258.350 us; speedup 1.0000x reference)
//
#include <hip/hip_runtime.h>

// Problem constants (B=2048, F=512, U=512, G=64, REG_STRENGTH=1.0)
#define B_SZ 2048
#define F_SZ 512
#define U_SZ 512
#define G_SZ 64
#define REG_STRENGTH 1.0f

// prep: histogram/prefix(shfl-scan)/scatter + workspace zeroing (proven).
// gemm: BARRIER-FREE K-loop. Wave = (group g, 16-col tile ct, k-half kh).
//   MFMA fragments are 8 CONSECUTIVE k per lane -> load them STRAIGHT from
//   global as 2x dwordx4 (wave = 16 rows x 1 full 128B line = 16 fully-used
//   segments/instr; r3's failure was 64 quarter-used segments). No LDS
//   staging, no per-step barrier (r4/r9 lesson: any K-step barrier locks the
//   kernel at 43-63 us), 1-step-ahead rotation in named SSA temps (r4-proven;
//   no asm barriers -> no r5-r8 scratch pathology). The two k-half waves
//   combine via 4KB LDS + one barrier at the END of each row-chunk.
#define THREADS 128
#define NBLOCKS 2048       // bid = ct*64 + g -> bid%8 == g%8 (XCD co-location)
#define NKS 8              // k-steps per wave (32 k each; half of F=512)

typedef float f32x4 __attribute__((ext_vector_type(4)));
typedef __bf16 bf16x8 __attribute__((ext_vector_type(8)));

#define MFMA(a, b, c) __builtin_amdgcn_mfma_f32_16x16x32_bf16((a), (b), (c), 0, 0, 0)

// fp32 -> (hi, lo) bf16 split (RNE). Dropped lo*lo matmul term is O(2^-18):
// fp32-grade accuracy (absmax 0.015625 every round since r1).
static __device__ __forceinline__ void cvt8(const f32x4 a, const f32x4 b,
                                            bf16x8& h, bf16x8& l) {
#pragma unroll
  for (int i = 0; i < 4; ++i) {
    const __bf16 t = (__bf16)a[i];
    h[i] = t;
    l[i] = (__bf16)(a[i] - (float)t);
  }
#pragma unroll
  for (int i = 0; i < 4; ++i) {
    const __bf16 t = (__bf16)b[i];
    h[4 + i] = t;
    l[4 + i] = (__bf16)(b[i] - (float)t);
  }
}

// ---------------------------------------------------------------------------
// Kernel A: histogram -> shfl scan -> scatter; zeroes wsf/done.
// ---------------------------------------------------------------------------
__global__ __launch_bounds__(1024) void prep_kernel(
    const int* __restrict__ gid, int* __restrict__ counts,
    int* __restrict__ rowstart, int* __restrict__ order,
    float* __restrict__ wsf, unsigned* __restrict__ done) {
  __shared__ int cnt_s[G_SZ];
  __shared__ int cur_s[G_SZ];
  const int tid = threadIdx.x;

  if (tid < G_SZ) cnt_s[tid] = 0;
  if (tid == 0) { wsf[0] = 0.0f; *done = 0u; }
  __syncthreads();

  for (int b = tid; b < B_SZ; b += 1024) atomicAdd(&cnt_s[gid[b]], 1);
  __syncthreads();

  if (tid < G_SZ) {  // wave 0: shfl inclusive scan -> exclusive
    const int c = cnt_s[tid];
    int inc = c;
#pragma unroll
    for (int o = 1; o < G_SZ; o <<= 1) {
      const int t = __shfl_up(inc, o, 64);
      if (tid >= o) inc += t;
    }
    counts[tid] = c;
    rowstart[tid] = inc - c;
    cur_s[tid] = inc - c;
  }
  __syncthreads();

  for (int b = tid; b < B_SZ; b += 1024) {
    int pos = atomicAdd(&cur_s[gid[b]], 1);
    order[pos] = b;
  }
}

// ---------------------------------------------------------------------------
// Kernel B: grouped GEMM, direct-fragment streaming, k-split across the
// block's 2 waves, fused reg loss + finalize.
// ---------------------------------------------------------------------------
__global__ __launch_bounds__(THREADS, 2) void gemm_kernel(
    const float* __restrict__ x, const float* __restrict__ w_mu,
    const float* __restrict__ b_mu, const float* __restrict__ w0_mu,
    const float* __restrict__ b0_mu, float* __restrict__ out,
    float* __restrict__ wsf, unsigned* __restrict__ done,
    const int* __restrict__ counts, const int* __restrict__ rowstart,
    const int* __restrict__ order) {
  __shared__ float comb[4 * 256];  // [mt][lane*4+j] partials, 4 KB

  const int bid = blockIdx.x;
  const int g = bid & 63;   // bid%8 == g%8 -> a group's blocks share an XCD
  const int ct = bid >> 6;  // 16-col tile 0..31
  const int n0 = ct << 4;

  const int tid = threadIdx.x;
  const int lane = tid & 63;
  const int kh = tid >> 6;    // k-half 0..1 (k in [kh*256, kh*256+256))
  const int llo = lane & 15;  // frag row (A) / col (B) within 16-tile
  const int lhi = lane >> 4;  // frag k-subchunk (8 consecutive k at 8*lhi)

  const int cnt = counts[g];

  if (cnt > 0) {
    const int rs = rowstart[g];
    const int mycol = n0 + llo;
    const int kbase = (kh << 8) + (lhi << 3);
    const float* __restrict__ wp =
        w_mu + ((size_t)g << 18) + ((size_t)mycol << 9) + kbase;
    const float* __restrict__ w0p = w0_mu + ((size_t)mycol << 9) + kbase;

    float regp = 0.0f;
    if (ct == 0) {  // fused bias reg-loss, once per group
#pragma unroll
      for (int u = 0; u < 4; ++u) {
        const int idx = (u << 7) + tid;
        const float d = b_mu[(g << 9) + idx] - b0_mu[idx];
        regp += d * d;
      }
    }

    for (int mc = 0; mc < cnt; mc += 64) {  // one pass in practice (cnt<=64)
      const int rc = min(64, cnt - mc);
      const int mts = (rc + 15) >> 4;  // active 16-row m-tiles (1..4)
      const bool doreg = (mc == 0);

      const float* __restrict__ xq[4];
#pragma unroll
      for (int mt = 0; mt < 4; ++mt) {
        int sl = mc + (mt << 4) + llo;
        if (sl >= cnt) sl = cnt - 1;  // dup row; never stored
        xq[mt] = x + ((size_t)order[rs + sl] << 9) + kbase;
      }

      f32x4 acc[4];
#pragma unroll
      for (int mt = 0; mt < 4; ++mt) acc[mt] = (f32x4){0.f, 0.f, 0.f, 0.f};

      // prefetch k-step 0 fragments (2x dwordx4 each, contiguous 32B/lane)
      f32x4 wa = *(const f32x4*)(wp);
      f32x4 wb = *(const f32x4*)(wp + 4);
      f32x4 xa[4], xb[4];
#pragma unroll
      for (int mt = 0; mt < 4; ++mt) {
        if (mt < mts) {
          xa[mt] = *(const f32x4*)(xq[mt]);
          xb[mt] = *(const f32x4*)(xq[mt] + 4);
        }
      }

      // ---- barrier-free K loop: 8 unrolled steps, 1-step-ahead rotation ----
#pragma unroll
      for (int ks = 0; ks < NKS; ++ks) {
        const int ko = ks << 5;
        f32x4 wan, wbn, xan[4], xbn[4];
        if (ks + 1 < NKS) {  // issue next step's loads before compute
          wan = *(const f32x4*)(wp + ko + 32);
          wbn = *(const f32x4*)(wp + ko + 36);
#pragma unroll
          for (int mt = 0; mt < 4; ++mt) {
            if (mt < mts) {
              xan[mt] = *(const f32x4*)(xq[mt] + ko + 32);
              xbn[mt] = *(const f32x4*)(xq[mt] + ko + 36);
            }
          }
        }
        if (doreg) {  // fused W reg-loss: each W element visited exactly once
          const f32x4 za = *(const f32x4*)(w0p + ko);
          const f32x4 zb = *(const f32x4*)(w0p + ko + 4);
#pragma unroll
          for (int i = 0; i < 4; ++i) {
            const float d0 = wa[i] - za[i], d1 = wb[i] - zb[i];
            regp += d0 * d0 + d1 * d1;
          }
        }
        bf16x8 wh, wl;
        cvt8(wa, wb, wh, wl);
#pragma unroll
        for (int mt = 0; mt < 4; ++mt) {
          if (mt < mts) {
            bf16x8 ah, al;
            cvt8(xa[mt], xb[mt], ah, al);
            acc[mt] = MFMA(ah, wh, acc[mt]);
            acc[mt] = MFMA(ah, wl, acc[mt]);
            acc[mt] = MFMA(al, wh, acc[mt]);
          }
        }
        if (ks + 1 < NKS) {  // rotate (pure SSA renaming after unroll)
          wa = wan; wb = wbn;
#pragma unroll
          for (int mt = 0; mt < 4; ++mt) {
            if (mt < mts) { xa[mt] = xan[mt]; xb[mt] = xbn[mt]; }
          }
        }
      }

      // ---- combine the two k-halves via LDS; kh==0 adds bias + stores ----
      __syncthreads();  // also guards comb reuse across mc chunks
      if (kh == 1) {
#pragma unroll
        for (int mt = 0; mt < 4; ++mt)
          if (mt < mts) *(f32x4*)&comb[(mt << 8) + (lane << 2)] = acc[mt];
      }
      __syncthreads();
      if (kh == 0) {
        const float bias = b_mu[(g << 9) + mycol];
#pragma unroll
        for (int mt = 0; mt < 4; ++mt) {
          if (mt < mts) {
            const f32x4 oth = *(const f32x4*)&comb[(mt << 8) + (lane << 2)];
#pragma unroll
            for (int j = 0; j < 4; ++j) {
              // D layout: row = 4*lhi + j (within 16-row tile), col = llo
              const int slot = mc + (mt << 4) + (lhi << 2) + j;
              if (slot < cnt) {
                out[(size_t)order[rs + slot] * U_SZ + mycol] =
                    acc[mt][j] + oth[j] + bias;
              }
            }
          }
        }
      }
    }

    // ---- wave-level reduce of reg partials, weight by cnt, one atomic ----
#pragma unroll
    for (int o = 32; o > 0; o >>= 1) regp += __shfl_down(regp, o, 64);
    if (lane == 0) atomicAdd(wsf, (float)cnt * regp);
  }

  // fused finalize: last block writes the reg-loss scalar
  if (tid == 0) {
    __threadfence();
    if (atomicAdd(done, 1u) == (unsigned)(NBLOCKS - 1)) {
      const float v = atomicAdd(wsf, 0.0f);  // coherent device-scope read
      out[(size_t)B_SZ * U_SZ] = REG_STRENGTH * v;
    }
  }
}

extern "C" void kernel_launch(void* const* d_in, const int* in_sizes, int n_in,
                              void* d_out, int out_size, void* d_ws,
                              size_t ws_size, hipStream_t stream) {
  (void)in_sizes; (void)n_in; (void)out_size; (void)ws_size;
  const float* x     = (const float*)d_in[0];
  const int*   gid   = (const int*)d_in[1];
  const float* w_mu  = (const float*)d_in[2];
  const float* b_mu  = (const float*)d_in[3];
  const float* w0_mu = (const float*)d_in[4];
  const float* b0_mu = (const float*)d_in[5];

  float*    wsf      = (float*)d_ws;         // [0]
  unsigned* done     = (unsigned*)d_ws + 1;  // [1]
  int*      counts   = (int*)d_ws + 2;
  int*      rowstart = (int*)d_ws + 2 + G_SZ;
  int*      order    = (int*)d_ws + 2 + 2 * G_SZ;

  prep_kernel<<<1, 1024, 0, stream>>>(gid, counts, rowstart, order, wsf, done);
  gemm_kernel<<<NBLOCKS, THREADS, 0, stream>>>(
      x, w_mu, b_mu, w0_mu, b0_mu, (float*)d_out, wsf, done,
      counts, rowstart, order);
}